// Round 10
// baseline (25031.490 us; speedup 1.0000x reference)
//
#include <hip/hip_runtime.h>
#include <hip/hip_bf16.h>

#define T_STEPS 4096
#define I_DIM   512
#define H_DIM   2048
#define O_DIM   128
#define NBLK    512   // 2 blocks/CU
#define THREADS 512   // 8 waves; 2 waves per hidden unit -> 4 units/block
#define SENTINEL 2.0f // |h| = |o*tanh(c)| <= 1.0 < 2.0, so 2.0f is unreachable

// Opaque pin: forbids rematerialization of weight regs from memory.
#define PIN2(v) asm volatile("" : "+v"((v).x), "+v"((v).y))

__global__ void fill_sentinel(float4* __restrict__ p)
{
    p[(size_t)blockIdx.x * blockDim.x + threadIdx.x] =
        make_float4(SENTINEL, SENTINEL, SENTINEL, SENTINEL);
}

// Persistent LSTM, 2 waves per hidden unit (gate-pair each):
//   wave p=0 owns gates (i,f), p=1 owns (g,o) and the cell state c.
// Per-lane: 64 fp32 W_hh + 16 fp32 W_ih slices -> ~105 VGPR, fits the
// backend's 128-VGPR / 4-waves-per-SIMD sweet spot with NO spills
// (R7/R8 showed the allocator refuses >128 VGPRs and spills instead).
// __launch_bounds__(512,4) hard-caps VGPR at 128 -> exactly 2 blocks/CU
// fit -> all 512 blocks co-resident -> data-spin (sentinel hbuf,
// write-once rows) cannot deadlock.
__global__ __launch_bounds__(THREADS, 4)
void lstm_persistent(const float* __restrict__ x,      // [T, I]
                     const float* __restrict__ W_ih,   // [4H, I]
                     const float* __restrict__ W_hh,   // [4H, H]
                     const float* __restrict__ b_ih,   // [4H]
                     const float* __restrict__ b_hh,   // [4H]
                     float* __restrict__ hbuf)         // [T, H] (ws, sentinel)
{
    const int tid  = threadIdx.x;
    const int wave = tid >> 6;
    const int lane = tid & 63;
    const int u    = wave >> 1;          // unit within block (0..3)
    const int p    = wave & 1;           // gate pair: 0 -> (i,f), 1 -> (g,o)
    const int j    = blockIdx.x * 4 + u; // hidden unit (0..2047)

    // ---- prologue: weight slices -> registers ----
    // wh2[q][c] = W_hh[(2p+q)*H + j][lane*32 + 2c .. +1]  (64 floats)
    // wx2[q][c] = W_ih[(2p+q)*H + j][lane*8  + 2c .. +1]  (16 floats)
    float2 wh2[2][16];
    float2 wx2[2][4];
    float  bs0, bs1;
    {
        const int r0 = (2 * p + 0) * H_DIM + j;
        const int r1 = (2 * p + 1) * H_DIM + j;
        const float2* wp0 = reinterpret_cast<const float2*>(
            W_hh + (size_t)r0 * H_DIM + lane * 32);
        const float2* wp1 = reinterpret_cast<const float2*>(
            W_hh + (size_t)r1 * H_DIM + lane * 32);
        #pragma unroll
        for (int c = 0; c < 16; ++c) { wh2[0][c] = wp0[c]; wh2[1][c] = wp1[c]; }
        const float2* xp0 = reinterpret_cast<const float2*>(
            W_ih + (size_t)r0 * I_DIM + lane * 8);
        const float2* xp1 = reinterpret_cast<const float2*>(
            W_ih + (size_t)r1 * I_DIM + lane * 8);
        #pragma unroll
        for (int c = 0; c < 4; ++c) { wx2[0][c] = xp0[c]; wx2[1][c] = xp1[c]; }
        bs0 = b_ih[r0] + b_hh[r0];
        bs1 = b_ih[r1] + b_hh[r1];
    }
    #pragma unroll
    for (int q = 0; q < 2; ++q) {
        #pragma unroll
        for (int c = 0; c < 16; ++c) PIN2(wh2[q][c]);
        #pragma unroll
        for (int c = 0; c < 4; ++c)  PIN2(wx2[q][c]);
    }

    // LDS. hstage: slice l at dword 34*l (b64 reads conflict-free).
    // xlds: slice l at dword 10*l (b64 reads conflict-free). gsum: exchange.
    __shared__ float hstage[64 * 34];           // 8704 B
    __shared__ float xlds[2][64 * 10];          // 5120 B
    __shared__ float gsum[4][2];

    xlds[0][10 * (tid >> 3) + (tid & 7)] = x[tid];   // stage x[0]
    __syncthreads();

    float c = 0.0f;   // cell state (meaningful in p==1 waves, uniform)

    for (int t = 0; t < T_STEPS; ++t) {
        const int cur = t & 1;

        // ---- issue h_{t-1} poll-loads FIRST (RTT overlaps x-dot) ----
        float hv0 = 0.f, hv1 = 0.f, hv2 = 0.f, hv3 = 0.f;
        const float* hp = hbuf + (size_t)(t - 1) * H_DIM + tid;
        if (t > 0) {
            hv0 = __hip_atomic_load(hp + 0 * THREADS, __ATOMIC_RELAXED,
                                    __HIP_MEMORY_SCOPE_AGENT);
            hv1 = __hip_atomic_load(hp + 1 * THREADS, __ATOMIC_RELAXED,
                                    __HIP_MEMORY_SCOPE_AGENT);
            hv2 = __hip_atomic_load(hp + 2 * THREADS, __ATOMIC_RELAXED,
                                    __HIP_MEMORY_SCOPE_AGENT);
            hv3 = __hip_atomic_load(hp + 3 * THREADS, __ATOMIC_RELAXED,
                                    __HIP_MEMORY_SCOPE_AGENT);
        }

        // ---- prefetch x[t+1] ----
        if (t + 1 < T_STEPS) {
            xlds[cur ^ 1][10 * (tid >> 3) + (tid & 7)] =
                x[(size_t)(t + 1) * I_DIM + tid];
        }

        // ---- x-dot (2 gates, 8 floats/lane), conflict-free b64 ----
        float a0 = 0.f, a1 = 0.f;
        {
            const float* xb = &xlds[cur][0];
            #pragma unroll
            for (int cc = 0; cc < 4; ++cc) {
                const float2 xv =
                    *reinterpret_cast<const float2*>(xb + 10 * lane + 2 * cc);
                a0 = fmaf(wx2[0][cc].x, xv.x, fmaf(wx2[0][cc].y, xv.y, a0));
                a1 = fmaf(wx2[1][cc].x, xv.x, fmaf(wx2[1][cc].y, xv.y, a1));
            }
        }

        if (t > 0) {
            // ---- data-spin until all 4 h values are published ----
            while (hv0 == SENTINEL || hv1 == SENTINEL ||
                   hv2 == SENTINEL || hv3 == SENTINEL) {
                __builtin_amdgcn_s_sleep(1);
                hv0 = __hip_atomic_load(hp + 0 * THREADS, __ATOMIC_RELAXED,
                                        __HIP_MEMORY_SCOPE_AGENT);
                hv1 = __hip_atomic_load(hp + 1 * THREADS, __ATOMIC_RELAXED,
                                        __HIP_MEMORY_SCOPE_AGENT);
                hv2 = __hip_atomic_load(hp + 2 * THREADS, __ATOMIC_RELAXED,
                                        __HIP_MEMORY_SCOPE_AGENT);
                hv3 = __hip_atomic_load(hp + 3 * THREADS, __ATOMIC_RELAXED,
                                        __HIP_MEMORY_SCOPE_AGENT);
            }
            // ---- stage h_{t-1}: value g -> hstage[34*(g>>5) + (g&31)] ----
            hstage[34 * ((tid + 0 * THREADS) >> 5) + ((tid + 0 * THREADS) & 31)] = hv0;
            hstage[34 * ((tid + 1 * THREADS) >> 5) + ((tid + 1 * THREADS) & 31)] = hv1;
            hstage[34 * ((tid + 2 * THREADS) >> 5) + ((tid + 2 * THREADS) & 31)] = hv2;
            hstage[34 * ((tid + 3 * THREADS) >> 5) + ((tid + 3 * THREADS) & 31)] = hv3;
        }
        __syncthreads();   // (A) hstage publish; fences xlds buffers

        if (t > 0) {
            // ---- h-dot: 32 floats/lane x 2 gates, conflict-free b64 ----
            const float* hb = hstage + 34 * lane;
            #pragma unroll
            for (int cc = 0; cc < 16; ++cc) {
                const float2 hv =
                    *reinterpret_cast<const float2*>(hb + 2 * cc);
                a0 = fmaf(wh2[0][cc].x, hv.x, fmaf(wh2[0][cc].y, hv.y, a0));
                a1 = fmaf(wh2[1][cc].x, hv.x, fmaf(wh2[1][cc].y, hv.y, a1));
            }
        }

        // ---- butterfly: all lanes get both gate sums (6 levels x 2) ----
        #pragma unroll
        for (int m = 1; m < 64; m <<= 1) {
            a0 += __shfl_xor(a0, m, 64);
            a1 += __shfl_xor(a1, m, 64);
        }
        const float pre0 = a0 + bs0;
        const float pre1 = a1 + bs1;

        if (p == 0 && lane == 0) {     // publish (i,f) pre-activations
            gsum[u][0] = pre0;
            gsum[u][1] = pre1;
        }
        __syncthreads();   // (C) gsum exchange

        if (p == 1) {
            const float pi = gsum[u][0];
            const float pf = gsum[u][1];
            const float si = 1.0f / (1.0f + __expf(-pi));
            const float sf = 1.0f / (1.0f + __expf(-pf));
            const float gt = 1.0f - 2.0f / (1.0f + __expf(2.0f * pre0));
            const float so = 1.0f / (1.0f + __expf(-pre1));

            c = fmaf(sf, c, si * gt);
            const float tc = 1.0f - 2.0f / (1.0f + __expf(2.0f * c));
            const float h_new = so * tc;   // |h_new| <= 1.0 < SENTINEL

            if (lane == 0) {
                __hip_atomic_store(hbuf + (size_t)t * H_DIM + j, h_new,
                                   __ATOMIC_RELAXED, __HIP_MEMORY_SCOPE_AGENT);
            }
        }
        __syncthreads();   // (B) hstage/gsum reuse boundary
    }
}

// WdT[k][o] = W_d[o][k]  (1 MB, one-time, makes final GEMM loads coalesced)
__global__ void transpose_wd(const float* __restrict__ W_d,
                             float* __restrict__ WdT)
{
    const int idx = blockIdx.x * blockDim.x + threadIdx.x;
    const int o = idx & (O_DIM - 1);
    const int k = idx >> 7;
    if (k < H_DIM) WdT[(size_t)k * O_DIM + o] = W_d[(size_t)o * H_DIM + k];
}

// out[t][o] = b_d[o] + sum_k hs[t][k] * W_d[o][k]
#define TB 8
__global__ __launch_bounds__(256)
void dense_out(const float* __restrict__ hbuf, const float* __restrict__ WdT,
               const float* __restrict__ b_d, float* __restrict__ out)
{
    __shared__ float hs[TB][H_DIM];   // 64 KB
    const int t0 = blockIdx.x * TB;

    for (int i = threadIdx.x; i < TB * H_DIM / 4; i += 256) {
        reinterpret_cast<float4*>(&hs[0][0])[i] =
            reinterpret_cast<const float4*>(hbuf + (size_t)t0 * H_DIM)[i];
    }
    __syncthreads();

    const int o  = threadIdx.x & (O_DIM - 1);
    const int th = threadIdx.x >> 7;            // 0..1 -> 4 timesteps each
    float a0 = b_d[o], a1 = a0, a2 = a0, a3 = a0;
    for (int k = 0; k < H_DIM; ++k) {
        const float w = WdT[(size_t)k * O_DIM + o];
        a0 = fmaf(hs[th * 4 + 0][k], w, a0);
        a1 = fmaf(hs[th * 4 + 1][k], w, a1);
        a2 = fmaf(hs[th * 4 + 2][k], w, a2);
        a3 = fmaf(hs[th * 4 + 3][k], w, a3);
    }
    out[(size_t)(t0 + th * 4 + 0) * O_DIM + o] = a0;
    out[(size_t)(t0 + th * 4 + 1) * O_DIM + o] = a1;
    out[(size_t)(t0 + th * 4 + 2) * O_DIM + o] = a2;
    out[(size_t)(t0 + th * 4 + 3) * O_DIM + o] = a3;
}

extern "C" void kernel_launch(void* const* d_in, const int* in_sizes, int n_in,
                              void* d_out, int out_size, void* d_ws, size_t ws_size,
                              hipStream_t stream)
{
    (void)in_sizes; (void)n_in; (void)out_size; (void)ws_size;
    const float* x    = (const float*)d_in[0];
    const float* W_ih = (const float*)d_in[1];
    const float* W_hh = (const float*)d_in[2];
    const float* b_ih = (const float*)d_in[3];
    const float* b_hh = (const float*)d_in[4];
    const float* W_d  = (const float*)d_in[5];
    const float* b_d  = (const float*)d_in[6];
    float* out = (float*)d_out;

    char* ws = (char*)d_ws;
    float* hbuf = (float*)ws;                                   // 32 MB
    float* WdT  = (float*)(ws + (size_t)T_STEPS * H_DIM * 4);   // 1 MB

    fill_sentinel<<<(T_STEPS * H_DIM / 4) / 256, 256, 0, stream>>>(
        (float4*)hbuf);
    transpose_wd<<<(H_DIM * O_DIM) / 256, 256, 0, stream>>>(W_d, WdT);
    lstm_persistent<<<NBLK, THREADS, 0, stream>>>(x, W_ih, W_hh, b_ih, b_hh,
                                                  hbuf);
    dense_out<<<T_STEPS / TB, 256, 0, stream>>>(hbuf, WdT, b_d, out);
}